// Round 9
// baseline (20858.456 us; speedup 1.0000x reference)
//
#include <hip/hip_runtime.h>

#define Hd 1024
#define Sd 4096
#define G4 4096   // 4*H

typedef __attribute__((ext_vector_type(8))) short    bf16x8;
typedef __attribute__((ext_vector_type(8))) unsigned short u16x8;
typedef __attribute__((ext_vector_type(4))) unsigned short u16x4;
typedef __attribute__((ext_vector_type(4))) float    f32x4;

// ---- ws layout (bytes) ----
#define WS_WHH_F 0u                 // 4096*1024*2 = 8388608
#define WS_WIH_F 8388608u           // 8388608
#define WS_EMB_F 16777216u          // 8388608 (dead after gemm_k; comm reuses head)
#define WS_COMM  16777216u          // hat[2][512]dw + tags[2][32*32]dw + cnt[8] + winner
#define WS_XG    25165824u          // 4096*4096*2 = 33554432
#define WS_BIAS  58720256u          // 4096*4 = 16384

__device__ __forceinline__ float b2f(unsigned short u) {
    return __uint_as_float(((unsigned)u) << 16);
}
__device__ __forceinline__ unsigned short f2b(float f) {
    unsigned u = __float_as_uint(f);
    unsigned r = u + 0x7fffu + ((u >> 16) & 1u);   // RNE
    return (unsigned short)(r >> 16);
}
__device__ __forceinline__ float sigmoid_fast(float x) {
    return 1.f / (1.f + __expf(-x));   // inf-safe at both ends
}
__device__ __forceinline__ float tanh_fast(float x) {
    float e = __expf(2.f * fabsf(x));  // inf-safe: 2/(inf+1)=0 -> +-1
    return copysignf(1.f - 2.f / (e + 1.f), x);
}

// Pack a [R x 1024] f32 matrix (optionally row-gathered by idx) into MFMA
// A-fragment order: chunk(rb,kb) = 64 lanes x 8 bf16,
// elem(l,j) = src[rb*16 + (l&15)][kb*32 + (l>>4)*8 + j]
__global__ void pack_frag(const float* __restrict__ src, const int* __restrict__ idx,
                          unsigned short* __restrict__ dst) {
    const int rb = blockIdx.x;       // 0..255
    const int kb = blockIdx.y;       // 0..31
    const int l  = threadIdx.x;      // 0..63
    int row = rb * 16 + (l & 15);
    if (idx) row = idx[row];
    const float* s = src + (size_t)row * Hd + kb * 32 + ((l >> 4) & 3) * 8;
    float4 f0 = *(const float4*)s;
    float4 f1 = *(const float4*)(s + 4);
    u16x8 v;
    v[0]=f2b(f0.x); v[1]=f2b(f0.y); v[2]=f2b(f0.z); v[3]=f2b(f0.w);
    v[4]=f2b(f1.x); v[5]=f2b(f1.y); v[6]=f2b(f1.z); v[7]=f2b(f1.w);
    *(u16x8*)(dst + ((size_t)(rb * 32 + kb) * 64 + l) * 8) = v;
}

__global__ void init_k(const float* __restrict__ bih, const float* __restrict__ bhh,
                       float* __restrict__ bias) {
    const int i = blockIdx.x * 256 + threadIdx.x;   // 0..4095
    bias[i] = bih[i] + bhh[i];
}

// Init comm: hat[2][512]=0 (h_0 = 0), tags[2][1024]=0, cnt[8]=0, winner=~0.
// Runs AFTER gemm_k (comm aliases the then-dead emb_f region).
__global__ void zero_comm_k(unsigned* __restrict__ base) {
    const int i = blockIdx.x * 256 + threadIdx.x;   // 0..3327
    if (i < 3072) base[i] = 0u;                     // hat (1024) + tags (2048)
    else if (i < 3080) base[i] = 0u;                // cnt[8]
    else if (i == 3080) base[i] = 0xFFFFFFFFu;      // winner
}

// xg[s][n] = sum_k embs[s][k]*W_ih[n][k] + bias[n], bf16 out.
__global__ __launch_bounds__(256, 2)
void gemm_k(const unsigned short* __restrict__ Af, const unsigned short* __restrict__ Bf,
            const float* __restrict__ bias, unsigned short* __restrict__ xg) {
    const int w = threadIdx.x >> 6, l = threadIdx.x & 63;
    const int wid = blockIdx.x * 4 + w;      // 0..4095
    const int mg = wid >> 6;                 // 0..63
    const int ng = wid & 63;                 // 0..63

    f32x4 acc[4][4] = {};
    for (int kb = 0; kb < 32; ++kb) {
        bf16x8 a[4], b[4];
#pragma unroll
        for (int mi = 0; mi < 4; ++mi)
            a[mi] = *(const bf16x8*)(Af + (((size_t)(mg * 4 + mi) * 32 + kb) * 64 + l) * 8);
#pragma unroll
        for (int ni = 0; ni < 4; ++ni)
            b[ni] = *(const bf16x8*)(Bf + (((size_t)(ng * 4 + ni) * 32 + kb) * 64 + l) * 8);
#pragma unroll
        for (int mi = 0; mi < 4; ++mi)
#pragma unroll
            for (int ni = 0; ni < 4; ++ni)
                acc[mi][ni] = __builtin_amdgcn_mfma_f32_16x16x32_bf16(a[mi], b[ni], acc[mi][ni], 0, 0, 0);
    }
    const int r4 = (l >> 4) * 4, c = l & 15;
#pragma unroll
    for (int ni = 0; ni < 4; ++ni) {
        const int col = ng * 64 + ni * 16 + c;
        const float bv = bias[col];
#pragma unroll
        for (int mi = 0; mi < 4; ++mi) {
            const int rowb = mg * 64 + mi * 16 + r4;
#pragma unroll
            for (int i = 0; i < 4; ++i)
                xg[(size_t)(rowb + i) * G4 + col] = f2b(acc[mi][ni][i] + bv);
        }
    }
}

// Persistent LSTM scan, all-atomic exchange. 256 elector WGs; first XCD to
// register 32 wins; worker rho owns h[rho*32, rho*32+32). Wave w = gate w
// (2 row-blocks, 64 MFMAs, W_hh in 256 VGPRs). Producer: h via atomic_swap
// (no-ret) -> vmcnt(0) -> tag via atomic_swap. Consumer: tag poll via
// returning atomic_or(.,0) (drained each sample), then h via 2 returning
// atomic_or per thread. Atomics are coherent at their execution point
// regardless of where that is -> correctness is scope-independent; speed
// tests the XCD-local-L2 hypothesis. All spins guard-bounded.
__global__ __launch_bounds__(256, 1)
void scan_k(const unsigned short* __restrict__ Wf, const unsigned short* __restrict__ xg,
            unsigned* __restrict__ base, float* __restrict__ out) {
    __shared__ unsigned h_sw[512];        // full h as 512 dwords (1024 bf16)
    __shared__ float g_lds[128];          // [gate 0..3][lh 0..31]
    __shared__ int s_role;

    unsigned* hat    = base;              // [2][512] dwords (h payload)
    unsigned* tags   = base + 1024;       // [2][32 roles * 32-dword stride]
    unsigned* cnt    = base + 3072;       // [8]
    unsigned* winner = base + 3080;

    // ---- election: first XCD to register 32 WGs wins (r7-proven) ----
    if (threadIdx.x == 0) {
        unsigned xcc;
        asm volatile("s_getreg_b32 %0, hwreg(HW_REG_XCC_ID)" : "=s"(xcc));
        xcc &= 7u;
        unsigned rho = atomicAdd(&cnt[xcc], 1u);
        int role = -1;
        if (rho < 32u) {
            if (rho == 31u) atomicCAS(winner, 0xFFFFFFFFu, xcc);
            unsigned wv = 0xFFFFFFFFu;
            int spin = 0;
            while ((wv = __hip_atomic_load(winner, __ATOMIC_RELAXED,
                                           __HIP_MEMORY_SCOPE_AGENT)) == 0xFFFFFFFFu
                   && ++spin < (1 << 20))
                __builtin_amdgcn_s_sleep(8);
            if (wv == xcc) role = (int)rho;
        }
        s_role = role;
    }
    __syncthreads();
    const int role = s_role;
    if (role < 0) return;

    const int tid = threadIdx.x;
    const int w = tid >> 6, l = tid & 63;
    const int rb0 = (w << 6) + role * 2;   // first of 2 row-blocks (gate w)

    bf16x8 wfrag[64];                      // 256 VGPRs of W_hh
#pragma unroll
    for (int kb = 0; kb < 32; ++kb) {
        wfrag[kb * 2]     = *(const bf16x8*)(Wf + (((size_t)rb0       * 32 + kb) * 64 + l) * 8);
        wfrag[kb * 2 + 1] = *(const bf16x8*)(Wf + (((size_t)(rb0 + 1) * 32 + kb) * 64 + l) * 8);
    }

    float c_reg = 0.f;                     // wave0 lanes<32: cell state
    const int hoff = ((l >> 4) & 3) * 8;
    const int r0 = (l >> 4) << 2;
    const unsigned short* h_ss = (const unsigned short*)h_sw;

    // xg t=0 prefetch (all waves; plain loads)
    u16x4 xv0 = {0,0,0,0}, xv1 = {0,0,0,0};
    if ((l & 15) == 0) {
        const unsigned short* xp = xg + (w << 10) + (role << 5) + r0;
        xv0 = *(const u16x4*)xp;
        xv1 = *(const u16x4*)(xp + 16);
    }

    for (int t = 0; t < Sd; ++t) {
        const unsigned tt = (unsigned)t;

        // ---- wave0: poll the 32 tags (returning atomics, drained) ----
        if (w == 0) {
            const unsigned* tp = tags + (t & 1) * 1024 + (l & 31) * 32;
            int guard = 0;
            unsigned o;
            while (true) {
                asm volatile("global_atomic_or %0, %1, %2, off sc0\n\ts_waitcnt vmcnt(0)"
                             : "=v"(o) : "v"(tp), "v"(0u) : "memory");
                __builtin_amdgcn_sched_barrier(0);
                if (!__any(o != tt)) break;
                if (++guard > 4096) break;    // bounded: wrong, never hang
                __builtin_amdgcn_s_sleep(1);
            }
        }
        __builtin_amdgcn_s_barrier();          // B1
        __builtin_amdgcn_sched_barrier(0);

        // ---- all threads: fetch h (2 returning atomics), stage to LDS ----
        {
            const unsigned* hp = hat + (t & 1) * 512 + tid * 2;
            unsigned ha, hb2;
            asm volatile("global_atomic_or %0, %1, %2, off sc0"
                         : "=v"(ha) : "v"(hp), "v"(0u) : "memory");
            asm volatile("global_atomic_or %0, %1, %2, off sc0"
                         : "=v"(hb2) : "v"(hp + 1), "v"(0u) : "memory");
            asm volatile("s_waitcnt vmcnt(0)" ::: "memory");
            __builtin_amdgcn_sched_barrier(0);
            h_sw[tid * 2]     = ha;
            h_sw[tid * 2 + 1] = hb2;
        }
        asm volatile("s_waitcnt lgkmcnt(0)" ::: "memory");
        __builtin_amdgcn_s_barrier();          // B2
        __builtin_amdgcn_sched_barrier(0);

        // ---- 64 MFMAs: 4 interleaved 16-deep chains ----
        f32x4 a00 = {0,0,0,0}, a01 = {0,0,0,0}, a10 = {0,0,0,0}, a11 = {0,0,0,0};
#pragma unroll
        for (int kb = 0; kb < 32; kb += 2) {
            bf16x8 hf0 = *(const bf16x8*)(h_ss + kb * 32 + hoff);
            bf16x8 hf1 = *(const bf16x8*)(h_ss + (kb + 1) * 32 + hoff);
            a00 = __builtin_amdgcn_mfma_f32_16x16x32_bf16(wfrag[kb * 2],           hf0, a00, 0, 0, 0);
            a10 = __builtin_amdgcn_mfma_f32_16x16x32_bf16(wfrag[kb * 2 + 1],       hf0, a10, 0, 0, 0);
            a01 = __builtin_amdgcn_mfma_f32_16x16x32_bf16(wfrag[(kb + 1) * 2],     hf1, a01, 0, 0, 0);
            a11 = __builtin_amdgcn_mfma_f32_16x16x32_bf16(wfrag[(kb + 1) * 2 + 1], hf1, a11, 0, 0, 0);
        }
        f32x4 acc0 = a00 + a01, acc1 = a10 + a11;

        if ((l & 15) == 0) {   // lanes 0,16,32,48: rows r0..r0+3 of each row-block
#pragma unroll
            for (int i = 0; i < 4; ++i) {
                g_lds[(w << 5) + r0 + i]      = acc0[i] + b2f(xv0[i]);
                g_lds[(w << 5) + 16 + r0 + i] = acc1[i] + b2f(xv1[i]);
            }
        }
        // waves 1-3: prefetch next xg (plain; compiler-tracked)
        if (w != 0 && (l & 15) == 0) {
            const unsigned short* xp = xg + (size_t)(t + 1) * G4 + (w << 10) + (role << 5) + r0;
            xv0 = *(const u16x4*)xp;
            xv1 = *(const u16x4*)(xp + 16);
        }
        asm volatile("s_waitcnt lgkmcnt(0)" ::: "memory");
        __builtin_amdgcn_s_barrier();          // B3
        __builtin_amdgcn_sched_barrier(0);

        // ---- wave0: LSTM cell for this WG's 32 h-lanes; all-atomic publish ----
        if (w == 0) {
            float h = 0.f; unsigned short hb = 0;
            if (l < 32) {
                float iv = sigmoid_fast(g_lds[l]);
                float fv = sigmoid_fast(g_lds[32 + l]);
                float gv = tanh_fast(g_lds[64 + l]);
                float ov = sigmoid_fast(g_lds[96 + l]);
                float c = fv * c_reg + iv * gv;
                c_reg = c;
                h = ov * tanh_fast(c);
                hb = f2b(h);
            }
            unsigned p = (unsigned)hb | ((unsigned)__shfl_xor((int)(unsigned)hb, 1, 64) << 16);
            if (l < 32 && !(l & 1)) {   // 16 dwords per role, via atomic swaps
                unsigned* dp = hat + ((t + 1) & 1) * 512 + (role << 4) + (l >> 1);
                asm volatile("global_atomic_swap %0, %1, off"
                             :: "v"(dp), "v"(p) : "memory");
            }
            // h swaps executed (ack = execution at the atomic point) before tag
            asm volatile("s_waitcnt vmcnt(0)" ::: "memory");
            __builtin_amdgcn_sched_barrier(0);
            if (l == 0) {
                unsigned* tq = tags + ((t + 1) & 1) * 1024 + role * 32;
                unsigned tv = tt + 1u;
                asm volatile("global_atomic_swap %0, %1, off"
                             :: "v"(tq), "v"(tv) : "memory");
            }
            // out[] stores AFTER the publish: HBM ack off the critical path
            if (l < 32) {
                out[(size_t)Hd + (size_t)t * Hd + (role << 5) + l] = h;   // outs[t]
                if (t == Sd - 1) out[(role << 5) + l] = h;                // final h
            }
            // wave0 xg prefetch (drained harmlessly by next poll's vmcnt(0))
            if ((l & 15) == 0) {
                const unsigned short* xp = xg + (size_t)(t + 1) * G4 + (w << 10) + (role << 5) + r0;
                xv0 = *(const u16x4*)xp;
                xv1 = *(const u16x4*)(xp + 16);
            }
        }
    }
}

extern "C" void kernel_launch(void* const* d_in, const int* in_sizes, int n_in,
                              void* d_out, int out_size, void* d_ws, size_t ws_size,
                              hipStream_t stream) {
    (void)in_sizes; (void)n_in; (void)out_size; (void)ws_size;
    const int*   x   = (const int*)  d_in[0];
    const float* emb = (const float*)d_in[1];
    const float* Wih = (const float*)d_in[2];
    const float* Whh = (const float*)d_in[3];
    const float* bih = (const float*)d_in[4];
    const float* bhh = (const float*)d_in[5];
    float* out = (float*)d_out;

    char* ws = (char*)d_ws;
    unsigned short* whh_f = (unsigned short*)(ws + WS_WHH_F);
    unsigned short* wih_f = (unsigned short*)(ws + WS_WIH_F);
    unsigned short* emb_f = (unsigned short*)(ws + WS_EMB_F);
    unsigned short* xgp   = (unsigned short*)(ws + WS_XG);
    float*          bias  = (float*)        (ws + WS_BIAS);
    unsigned*       comm  = (unsigned*)      (ws + WS_COMM);

    init_k     <<<16, 256, 0, stream>>>(bih, bhh, bias);
    pack_frag  <<<dim3(256, 32), 64, 0, stream>>>(Whh, nullptr, whh_f);
    pack_frag  <<<dim3(256, 32), 64, 0, stream>>>(Wih, nullptr, wih_f);
    pack_frag  <<<dim3(256, 32), 64, 0, stream>>>(emb, x,       emb_f);
    gemm_k     <<<1024, 256, 0, stream>>>(emb_f, wih_f, bias, xgp);
    zero_comm_k<<<13, 256, 0, stream>>>(comm);         // after gemm: comm aliases emb_f
    scan_k     <<<256, 256, 0, stream>>>(whh_f, xgp, comm, out);
}

// Round 10
// 11410.196 us; speedup vs baseline: 1.8281x; 1.8281x over previous
//
#include <hip/hip_runtime.h>

#define Hd 1024
#define Sd 4096
#define G4 4096   // 4*H

typedef __attribute__((ext_vector_type(8))) short    bf16x8;
typedef __attribute__((ext_vector_type(8))) unsigned short u16x8;
typedef __attribute__((ext_vector_type(4))) unsigned short u16x4;
typedef __attribute__((ext_vector_type(4))) unsigned u32x4;
typedef __attribute__((ext_vector_type(4))) float    f32x4;

// ---- ws layout (bytes) ----
#define WS_WHH_F 0u                 // 4096*1024*2 = 8388608
#define WS_WIH_F 8388608u           // 8388608
#define WS_EMB_F 16777216u          // 8388608 (dead after gemm_k; hrec reuses its head)
#define WS_HREC  16777216u          // 2 buffers x 256 chunks x 16B = 8192
#define WS_XG    25165824u          // 4096*4096*2 = 33554432
#define WS_BIAS  58720256u          // 4096*4 = 16384
                                    // NOTE: t=4095's xg t+1 prefetch reads the bias
                                    // region (in-bounds of d_ws, values unused).

__device__ __forceinline__ float b2f(unsigned short u) {
    return __uint_as_float(((unsigned)u) << 16);
}
__device__ __forceinline__ unsigned short f2b(float f) {
    unsigned u = __float_as_uint(f);
    unsigned r = u + 0x7fffu + ((u >> 16) & 1u);   // RNE
    return (unsigned short)(r >> 16);
}
__device__ __forceinline__ float sigmoid_fast(float x) {
    return 1.f / (1.f + __expf(-x));   // inf-safe at both ends
}
__device__ __forceinline__ float tanh_fast(float x) {
    float e = __expf(2.f * fabsf(x));  // inf-safe: 2/(inf+1)=0 -> +-1
    return copysignf(1.f - 2.f / (e + 1.f), x);
}

// Pack a [R x 1024] f32 matrix (optionally row-gathered by idx) into MFMA
// A-fragment order: chunk(rb,kb) = 64 lanes x 8 bf16,
// elem(l,j) = src[rb*16 + (l&15)][kb*32 + (l>>4)*8 + j]
__global__ void pack_frag(const float* __restrict__ src, const int* __restrict__ idx,
                          unsigned short* __restrict__ dst) {
    const int rb = blockIdx.x;       // 0..255
    const int kb = blockIdx.y;       // 0..31
    const int l  = threadIdx.x;      // 0..63
    int row = rb * 16 + (l & 15);
    if (idx) row = idx[row];
    const float* s = src + (size_t)row * Hd + kb * 32 + ((l >> 4) & 3) * 8;
    float4 f0 = *(const float4*)s;
    float4 f1 = *(const float4*)(s + 4);
    u16x8 v;
    v[0]=f2b(f0.x); v[1]=f2b(f0.y); v[2]=f2b(f0.z); v[3]=f2b(f0.w);
    v[4]=f2b(f1.x); v[5]=f2b(f1.y); v[6]=f2b(f1.z); v[7]=f2b(f1.w);
    *(u16x8*)(dst + ((size_t)(rb * 32 + kb) * 64 + l) * 8) = v;
}

__global__ void init_k(const float* __restrict__ bih, const float* __restrict__ bhh,
                       float* __restrict__ bias) {
    const int i = blockIdx.x * 256 + threadIdx.x;   // 0..4095
    bias[i] = bih[i] + bhh[i];
}

// zero BOTH hrec buffers (tags 0; garbage could alias a future tag).
__global__ void zero_hrec_k(unsigned* __restrict__ hrec) {
    hrec[blockIdx.x * 256 + threadIdx.x] = 0u;      // 2048 dwords
}

// xg[s][n] = sum_k embs[s][k]*W_ih[n][k] + bias[n], bf16 out.
__global__ __launch_bounds__(256, 2)
void gemm_k(const unsigned short* __restrict__ Af, const unsigned short* __restrict__ Bf,
            const float* __restrict__ bias, unsigned short* __restrict__ xg) {
    const int w = threadIdx.x >> 6, l = threadIdx.x & 63;
    const int wid = blockIdx.x * 4 + w;      // 0..4095
    const int mg = wid >> 6;                 // 0..63
    const int ng = wid & 63;                 // 0..63

    f32x4 acc[4][4] = {};
    for (int kb = 0; kb < 32; ++kb) {
        bf16x8 a[4], b[4];
#pragma unroll
        for (int mi = 0; mi < 4; ++mi)
            a[mi] = *(const bf16x8*)(Af + (((size_t)(mg * 4 + mi) * 32 + kb) * 64 + l) * 8);
#pragma unroll
        for (int ni = 0; ni < 4; ++ni)
            b[ni] = *(const bf16x8*)(Bf + (((size_t)(ng * 4 + ni) * 32 + kb) * 64 + l) * 8);
#pragma unroll
        for (int mi = 0; mi < 4; ++mi)
#pragma unroll
            for (int ni = 0; ni < 4; ++ni)
                acc[mi][ni] = __builtin_amdgcn_mfma_f32_16x16x32_bf16(a[mi], b[ni], acc[mi][ni], 0, 0, 0);
    }
    const int r4 = (l >> 4) * 4, c = l & 15;
#pragma unroll
    for (int ni = 0; ni < 4; ++ni) {
        const int col = ng * 64 + ni * 16 + c;
        const float bv = bias[col];
#pragma unroll
        for (int mi = 0; mi < 4; ++mi) {
            const int rowb = mg * 64 + mi * 16 + r4;
#pragma unroll
            for (int i = 0; i < 4; ++i)
                xg[(size_t)(rowb + i) * G4 + col] = f2b(acc[mi][ni][i] + bv);
        }
    }
}

// Persistent LSTM scan. 64 WGs x 256 thr. WG r owns h[r*16, r*16+16).
// Wave w = gate w (one 16-row block; 32 MFMAs; W_hh in 128 VGPRs loaded via
// ASM so the compiler cannot spill/reload them). Transport: r4-proven 256
// dual-tagged 16B chunks at LLC scope (sc0 sc1). Detection: staggered batch
// of 4 samples, FULLY DRAINED (vmcnt(0)) before any check -> no dangling
// loads ever. Cell redundant in all 4 waves; each wave publishes 1 chunk.
__global__ __launch_bounds__(256, 1)
void scan_k(const unsigned short* __restrict__ Wf, const unsigned short* __restrict__ xg,
            unsigned* __restrict__ hrec, float* __restrict__ out) {
    __shared__ unsigned h_sw[512];        // full h as 512 dwords (1024 bf16)
    __shared__ float g_lds[64];           // [gate 0..3][r 0..15]

    const int role = blockIdx.x;          // 0..63
    const int tid  = threadIdx.x;         // == this thread's chunk index
    const int w = tid >> 6, l = tid & 63;
    const int rb = (w << 6) + role;       // row-block: gate w rows role*16..+16

    // W_hh fragments via asm loads: outputs are opaque -> guaranteed resident.
    bf16x8 wfrag[32];                     // 128 VGPRs
#pragma unroll
    for (int kb = 0; kb < 32; ++kb) {
        const unsigned short* wp = Wf + (((size_t)rb * 32 + kb) * 64 + l) * 8;
        asm volatile("global_load_dwordx4 %0, %1, off" : "=v"(wfrag[kb]) : "v"(wp) : "memory");
    }
    asm volatile("s_waitcnt vmcnt(0)" ::: "memory");
    __builtin_amdgcn_sched_barrier(0);

    float c_reg = 0.f;                    // lanes l<16: cell state (redundant per wave)
    const int hoff = ((l >> 4) & 3) * 8;
    const int r0 = (l >> 4) << 2;
    const unsigned short* h_ss = (const unsigned short*)h_sw;

    // xg t=0 prefetch (plain loads; compiler-managed waits)
    u16x4 xv = {0, 0, 0, 0};
    if ((l & 15) == 0)
        xv = *(const u16x4*)(xg + (w << 10) + (role << 4) + r0);

    for (int t = 0; t < Sd; ++t) {
        const unsigned tt = (unsigned)t;
        const unsigned* gp = hrec + (t & 1) * 1024 + tid * 4;

        // ---- staggered-batch poll: 4 samples ~380cy apart, then full drain ----
        u32x4 p0, p1, p2, p3, got;
        int guard = 0;
        while (true) {
            asm volatile("global_load_dwordx4 %0, %1, off sc0 sc1" : "=v"(p0) : "v"(gp) : "memory");
            __builtin_amdgcn_s_sleep(6);
            asm volatile("global_load_dwordx4 %0, %1, off sc0 sc1" : "=v"(p1) : "v"(gp) : "memory");
            __builtin_amdgcn_s_sleep(6);
            asm volatile("global_load_dwordx4 %0, %1, off sc0 sc1" : "=v"(p2) : "v"(gp) : "memory");
            __builtin_amdgcn_s_sleep(6);
            asm volatile("global_load_dwordx4 %0, %1, off sc0 sc1" : "=v"(p3) : "v"(gp) : "memory");
            asm volatile("s_waitcnt vmcnt(0)" ::: "memory");   // NOTHING in flight past here
            __builtin_amdgcn_sched_barrier(0);
            const bool f0 = (p0[1] == tt) & (p0[3] == tt);
            const bool f1 = (p1[1] == tt) & (p1[3] == tt);
            const bool f2 = (p2[1] == tt) & (p2[3] == tt);
            const bool f3 = (p3[1] == tt) & (p3[3] == tt);
            got = f3 ? p3 : (f2 ? p2 : (f1 ? p1 : p0));
            if (!__any(!(f0 | f1 | f2 | f3))) break;
            if (++guard > 2048) break;     // bounded: wrong, never hang
        }

        // ---- stage h into LDS ----
        h_sw[tid * 2]     = got[0];
        h_sw[tid * 2 + 1] = got[2];
        asm volatile("s_waitcnt lgkmcnt(0)" ::: "memory");
        __builtin_amdgcn_s_barrier();                          // B1
        __builtin_amdgcn_sched_barrier(0);

        // ---- 32 MFMAs: 4 interleaved 8-deep chains ----
        f32x4 ac0 = {0,0,0,0}, ac1 = {0,0,0,0}, ac2 = {0,0,0,0}, ac3 = {0,0,0,0};
#pragma unroll
        for (int kb = 0; kb < 32; kb += 4) {
            bf16x8 h0 = *(const bf16x8*)(h_ss + (kb + 0) * 32 + hoff);
            bf16x8 h1 = *(const bf16x8*)(h_ss + (kb + 1) * 32 + hoff);
            bf16x8 h2 = *(const bf16x8*)(h_ss + (kb + 2) * 32 + hoff);
            bf16x8 h3 = *(const bf16x8*)(h_ss + (kb + 3) * 32 + hoff);
            ac0 = __builtin_amdgcn_mfma_f32_16x16x32_bf16(wfrag[kb + 0], h0, ac0, 0, 0, 0);
            ac1 = __builtin_amdgcn_mfma_f32_16x16x32_bf16(wfrag[kb + 1], h1, ac1, 0, 0, 0);
            ac2 = __builtin_amdgcn_mfma_f32_16x16x32_bf16(wfrag[kb + 2], h2, ac2, 0, 0, 0);
            ac3 = __builtin_amdgcn_mfma_f32_16x16x32_bf16(wfrag[kb + 3], h3, ac3, 0, 0, 0);
        }
        f32x4 acc = (ac0 + ac1) + (ac2 + ac3);

        if ((l & 15) == 0) {   // lanes 0,16,32,48 hold rows r0..r0+3 (col 0)
#pragma unroll
            for (int i = 0; i < 4; ++i)
                g_lds[(w << 4) + r0 + i] = acc[i] + b2f(xv[i]);
        }
        asm volatile("s_waitcnt lgkmcnt(0)" ::: "memory");
        __builtin_amdgcn_s_barrier();                          // B2
        __builtin_amdgcn_sched_barrier(0);

        // ---- LSTM cell, redundant in all 4 waves (lanes l<16) ----
        float h = 0.f; unsigned short hb = 0;
        if (l < 16) {
            float iv = sigmoid_fast(g_lds[l]);
            float fv = sigmoid_fast(g_lds[16 + l]);
            float gv = tanh_fast(g_lds[32 + l]);
            float ov = sigmoid_fast(g_lds[48 + l]);
            float c = fv * c_reg + iv * gv;
            c_reg = c;
            h = ov * tanh_fast(c);
            hb = f2b(h);
        }
        // wave w publishes chunk role*4+w = {h[4w..4w+1], tag, h[4w+2..4w+3], tag}
        unsigned p  = (unsigned)hb | ((unsigned)__shfl_xor((int)(unsigned)hb, 1, 64) << 16);
        unsigned p2v = (unsigned)__shfl((int)p, (l & ~3) + 2, 64);
        if (l == (w << 2)) {
            const unsigned tag = tt + 1u;
            u32x4 val = {p, tag, p2v, tag};
            unsigned* dst = hrec + ((t + 1) & 1) * 1024 + ((role << 2) + w) * 4;
            asm volatile("global_store_dwordx4 %0, %1, off sc0 sc1"
                         :: "v"(dst), "v"(val) : "memory");
        }
        // out[] and next-step xg AFTER the publish (off the producer critical path)
        if (l < 16) {
            out[(size_t)Hd + (size_t)t * Hd + (role << 4) + l] = h;   // outs[t]
            if (t == Sd - 1) out[(role << 4) + l] = h;                // final h
        }
        if ((l & 15) == 0)
            xv = *(const u16x4*)(xg + (size_t)(t + 1) * G4 + (w << 10) + (role << 4) + r0);
        // fire-and-forget stores: next poll's vmcnt(0) FIFO-drains the acks.
    }
}

extern "C" void kernel_launch(void* const* d_in, const int* in_sizes, int n_in,
                              void* d_out, int out_size, void* d_ws, size_t ws_size,
                              hipStream_t stream) {
    (void)in_sizes; (void)n_in; (void)out_size; (void)ws_size;
    const int*   x   = (const int*)  d_in[0];
    const float* emb = (const float*)d_in[1];
    const float* Wih = (const float*)d_in[2];
    const float* Whh = (const float*)d_in[3];
    const float* bih = (const float*)d_in[4];
    const float* bhh = (const float*)d_in[5];
    float* out = (float*)d_out;

    char* ws = (char*)d_ws;
    unsigned short* whh_f = (unsigned short*)(ws + WS_WHH_F);
    unsigned short* wih_f = (unsigned short*)(ws + WS_WIH_F);
    unsigned short* emb_f = (unsigned short*)(ws + WS_EMB_F);
    unsigned short* xgp   = (unsigned short*)(ws + WS_XG);
    float*          bias  = (float*)        (ws + WS_BIAS);
    unsigned*       hrec  = (unsigned*)      (ws + WS_HREC);

    init_k     <<<16, 256, 0, stream>>>(bih, bhh, bias);
    pack_frag  <<<dim3(256, 32), 64, 0, stream>>>(Whh, nullptr, whh_f);
    pack_frag  <<<dim3(256, 32), 64, 0, stream>>>(Wih, nullptr, wih_f);
    pack_frag  <<<dim3(256, 32), 64, 0, stream>>>(emb, x,       emb_f);
    gemm_k     <<<1024, 256, 0, stream>>>(emb_f, wih_f, bias, xgp);
    zero_hrec_k<<<8, 256, 0, stream>>>(hrec);          // after gemm: hrec aliases emb_f
    scan_k     <<<64, 256, 0, stream>>>(whh_f, xgp, hrec, out);
}

// Round 11
// 8350.952 us; speedup vs baseline: 2.4977x; 1.3663x over previous
//
#include <hip/hip_runtime.h>

#define Hd 1024
#define Sd 4096
#define G4 4096   // 4*H

typedef __attribute__((ext_vector_type(8))) short    bf16x8;
typedef __attribute__((ext_vector_type(8))) unsigned short u16x8;
typedef __attribute__((ext_vector_type(4))) unsigned short u16x4;
typedef __attribute__((ext_vector_type(4))) unsigned u32x4;
typedef __attribute__((ext_vector_type(4))) float    f32x4;

// ---- ws layout (bytes) ----
#define WS_WHH_F 0u                 // 4096*1024*2 = 8388608
#define WS_WIH_F 8388608u           // 8388608
#define WS_EMB_F 16777216u          // 8388608 (dead after gemm_k; hrec reuses its head)
#define WS_HREC  16777216u          // 2 buffers x 256 chunks x 16B = 8192
#define WS_XG    25165824u          // 4096*4096*2 = 33554432
#define WS_BIAS  58720256u          // 4096*4 = 16384
                                    // NOTE: t=4095's xg t+1 prefetch reads the bias
                                    // region (in-bounds of d_ws, values unused).

__device__ __forceinline__ float b2f(unsigned short u) {
    return __uint_as_float(((unsigned)u) << 16);
}
__device__ __forceinline__ unsigned short f2b(float f) {
    unsigned u = __float_as_uint(f);
    unsigned r = u + 0x7fffu + ((u >> 16) & 1u);   // RNE
    return (unsigned short)(r >> 16);
}
__device__ __forceinline__ float sigmoid_fast(float x) {
    return 1.f / (1.f + __expf(-x));   // inf-safe at both ends
}
__device__ __forceinline__ float tanh_fast(float x) {
    float e = __expf(2.f * fabsf(x));  // inf-safe: 2/(inf+1)=0 -> +-1
    return copysignf(1.f - 2.f / (e + 1.f), x);
}

// Pack a [R x 1024] f32 matrix (optionally row-gathered by idx) into MFMA
// A-fragment order: chunk(rb,kb) = 64 lanes x 8 bf16,
// elem(l,j) = src[rb*16 + (l&15)][kb*32 + (l>>4)*8 + j]
__global__ void pack_frag(const float* __restrict__ src, const int* __restrict__ idx,
                          unsigned short* __restrict__ dst) {
    const int rb = blockIdx.x;       // 0..255
    const int kb = blockIdx.y;       // 0..31
    const int l  = threadIdx.x;      // 0..63
    int row = rb * 16 + (l & 15);
    if (idx) row = idx[row];
    const float* s = src + (size_t)row * Hd + kb * 32 + ((l >> 4) & 3) * 8;
    float4 f0 = *(const float4*)s;
    float4 f1 = *(const float4*)(s + 4);
    u16x8 v;
    v[0]=f2b(f0.x); v[1]=f2b(f0.y); v[2]=f2b(f0.z); v[3]=f2b(f0.w);
    v[4]=f2b(f1.x); v[5]=f2b(f1.y); v[6]=f2b(f1.z); v[7]=f2b(f1.w);
    *(u16x8*)(dst + ((size_t)(rb * 32 + kb) * 64 + l) * 8) = v;
}

__global__ void init_k(const float* __restrict__ bih, const float* __restrict__ bhh,
                       float* __restrict__ bias) {
    const int i = blockIdx.x * 256 + threadIdx.x;   // 0..4095
    bias[i] = bih[i] + bhh[i];
}

// zero BOTH hrec buffers (tags 0; garbage could alias a future tag).
__global__ void zero_hrec_k(unsigned* __restrict__ hrec) {
    hrec[blockIdx.x * 256 + threadIdx.x] = 0u;      // 2048 dwords
}

// xg[s][n] = sum_k embs[s][k]*W_ih[n][k] + bias[n], bf16 out.
__global__ __launch_bounds__(256, 2)
void gemm_k(const unsigned short* __restrict__ Af, const unsigned short* __restrict__ Bf,
            const float* __restrict__ bias, unsigned short* __restrict__ xg) {
    const int w = threadIdx.x >> 6, l = threadIdx.x & 63;
    const int wid = blockIdx.x * 4 + w;      // 0..4095
    const int mg = wid >> 6;                 // 0..63
    const int ng = wid & 63;                 // 0..63

    f32x4 acc[4][4] = {};
    for (int kb = 0; kb < 32; ++kb) {
        bf16x8 a[4], b[4];
#pragma unroll
        for (int mi = 0; mi < 4; ++mi)
            a[mi] = *(const bf16x8*)(Af + (((size_t)(mg * 4 + mi) * 32 + kb) * 64 + l) * 8);
#pragma unroll
        for (int ni = 0; ni < 4; ++ni)
            b[ni] = *(const bf16x8*)(Bf + (((size_t)(ng * 4 + ni) * 32 + kb) * 64 + l) * 8);
#pragma unroll
        for (int mi = 0; mi < 4; ++mi)
#pragma unroll
            for (int ni = 0; ni < 4; ++ni)
                acc[mi][ni] = __builtin_amdgcn_mfma_f32_16x16x32_bf16(a[mi], b[ni], acc[mi][ni], 0, 0, 0);
    }
    const int r4 = (l >> 4) * 4, c = l & 15;
#pragma unroll
    for (int ni = 0; ni < 4; ++ni) {
        const int col = ng * 64 + ni * 16 + c;
        const float bv = bias[col];
#pragma unroll
        for (int mi = 0; mi < 4; ++mi) {
            const int rowb = mg * 64 + mi * 16 + r4;
#pragma unroll
            for (int i = 0; i < 4; ++i)
                xg[(size_t)(rowb + i) * G4 + col] = f2b(acc[mi][ni][i] + bv);
        }
    }
}

// Persistent LSTM scan. 32 WGs x 512 thr (8 waves). WG r owns h[r*32, r*32+32).
// Wave w: gate w>>1, rows r*32 + (w&1)*16 .. +16 (one 16-row block, 32 MFMAs,
// W_hh in 128 VGPRs -> no spill under launch_bounds(512,2)).
// Transport (r4-proven): 256 dual-tagged 16B chunks at LLC scope (sc0 sc1);
// threads 0..255 poll chunk tid with the drained single-sample loop, with an
// s_sleep(12) phase offset so sample 1 usually lands after the store arrives.
// Waves 4-7 skip polling (wait at B1). Cell redundant in all 8 waves; wave w
// publishes chunk role*8+w. No dangling VMEM anywhere.
__global__ __launch_bounds__(512, 2)
void scan_k(const unsigned short* __restrict__ Wf, const unsigned short* __restrict__ xg,
            unsigned* __restrict__ hrec, float* __restrict__ out) {
    __shared__ unsigned h_sw[512];        // full h as 512 dwords (1024 bf16)
    __shared__ float g_lds[128];          // [gate 0..3][lh 0..31]

    const int role = blockIdx.x;          // 0..31
    const int tid  = threadIdx.x;         // 0..511
    const int w = tid >> 6, l = tid & 63;
    const int gate = w >> 1, half = w & 1;
    const int rb = (gate << 6) + (role << 1) + half;   // row-block index in W packing

    bf16x8 wfrag[32];                     // 128 VGPRs of W_hh (compiler-resident)
#pragma unroll
    for (int kb = 0; kb < 32; ++kb)
        wfrag[kb] = *(const bf16x8*)(Wf + (((size_t)rb * 32 + kb) * 64 + l) * 8);

    float c_reg = 0.f;                    // lanes l<32: cell state (redundant per wave)
    const int hoff = ((l >> 4) & 3) * 8;  // bf16 offset within each 32-chunk of h
    const int r0 = (l >> 4) << 2;
    const unsigned short* h_ss = (const unsigned short*)h_sw;
    const int xbase = (gate << 10) + (role << 5) + (half << 4) + r0;

    // xg t=0 prefetch (plain loads; compiler-managed waits)
    u16x4 xv = {0, 0, 0, 0};
    if ((l & 15) == 0)
        xv = *(const u16x4*)(xg + xbase);

    for (int t = 0; t < Sd; ++t) {
        const unsigned tt = (unsigned)t;

        // ---- waves 0-3: poll own chunk (drained, phase-offset), stage to LDS ----
        if (tid < 256) {
            const unsigned* gp = hrec + (t & 1) * 1024 + tid * 4;
            u32x4 pA;
            __builtin_amdgcn_s_sleep(12);   // ~768cy < store-travel: sample 1 lands fresh
            int guard = 0;
            while (true) {
                asm volatile("global_load_dwordx4 %0, %1, off sc0 sc1\n\ts_waitcnt vmcnt(0)"
                             : "=v"(pA) : "v"(gp) : "memory");
                __builtin_amdgcn_sched_barrier(0);
                if (!__any((pA[1] != tt) | (pA[3] != tt))) break;
                if (++guard > 65536) break;   // bounded: wrong, never hang
                __builtin_amdgcn_s_sleep(1);
            }
            h_sw[tid * 2]     = pA[0];
            h_sw[tid * 2 + 1] = pA[2];
            asm volatile("s_waitcnt lgkmcnt(0)" ::: "memory");
        }
        __builtin_amdgcn_s_barrier();                          // B1
        __builtin_amdgcn_sched_barrier(0);

        // ---- 32 MFMAs: 4 interleaved 8-deep chains ----
        f32x4 ac0 = {0,0,0,0}, ac1 = {0,0,0,0}, ac2 = {0,0,0,0}, ac3 = {0,0,0,0};
#pragma unroll
        for (int kb = 0; kb < 32; kb += 4) {
            bf16x8 h0 = *(const bf16x8*)(h_ss + (kb + 0) * 32 + hoff);
            bf16x8 h1 = *(const bf16x8*)(h_ss + (kb + 1) * 32 + hoff);
            bf16x8 h2 = *(const bf16x8*)(h_ss + (kb + 2) * 32 + hoff);
            bf16x8 h3 = *(const bf16x8*)(h_ss + (kb + 3) * 32 + hoff);
            ac0 = __builtin_amdgcn_mfma_f32_16x16x32_bf16(wfrag[kb + 0], h0, ac0, 0, 0, 0);
            ac1 = __builtin_amdgcn_mfma_f32_16x16x32_bf16(wfrag[kb + 1], h1, ac1, 0, 0, 0);
            ac2 = __builtin_amdgcn_mfma_f32_16x16x32_bf16(wfrag[kb + 2], h2, ac2, 0, 0, 0);
            ac3 = __builtin_amdgcn_mfma_f32_16x16x32_bf16(wfrag[kb + 3], h3, ac3, 0, 0, 0);
        }
        f32x4 acc = (ac0 + ac1) + (ac2 + ac3);

        if ((l & 15) == 0) {   // lanes 0,16,32,48 hold rows r0..r0+3 (col 0)
#pragma unroll
            for (int i = 0; i < 4; ++i)
                g_lds[(gate << 5) + (half << 4) + r0 + i] = acc[i] + b2f(xv[i]);
        }
        asm volatile("s_waitcnt lgkmcnt(0)" ::: "memory");
        __builtin_amdgcn_s_barrier();                          // B2
        __builtin_amdgcn_sched_barrier(0);

        // ---- LSTM cell, redundant in all 8 waves (lanes l<32) ----
        float h = 0.f; unsigned short hb = 0;
        if (l < 32) {
            float iv = sigmoid_fast(g_lds[l]);
            float fv = sigmoid_fast(g_lds[32 + l]);
            float gv = tanh_fast(g_lds[64 + l]);
            float ov = sigmoid_fast(g_lds[96 + l]);
            float c = fv * c_reg + iv * gv;
            c_reg = c;
            h = ov * tanh_fast(c);
            hb = f2b(h);
        }
        // wave w publishes chunk role*8+w = {h[4w..4w+1], tag, h[4w+2..4w+3], tag}
        unsigned p   = (unsigned)hb | ((unsigned)__shfl_xor((int)(unsigned)hb, 1, 64) << 16);
        unsigned p2v = (unsigned)__shfl((int)p, (l & ~3) + 2, 64);
        if (l == (w << 2)) {
            const unsigned tag = tt + 1u;
            u32x4 val = {p, tag, p2v, tag};
            unsigned* dst = hrec + ((t + 1) & 1) * 1024 + ((role << 3) + w) * 4;
            asm volatile("global_store_dwordx4 %0, %1, off sc0 sc1"
                         :: "v"(dst), "v"(val) : "memory");
        }
        // out[] (wave 0 only) and next-step xg AFTER the publish
        if (w == 0 && l < 32) {
            out[(size_t)Hd + (size_t)t * Hd + (role << 5) + l] = h;   // outs[t]
            if (t == Sd - 1) out[(role << 5) + l] = h;                // final h
        }
        if ((l & 15) == 0)
            xv = *(const u16x4*)(xg + (size_t)(t + 1) * G4 + xbase);
        // per-wave FIFO: the compiler's wait for xv-use (and waves 0-3's poll
        // drains) retire the publish store before the same wave's next publish.
    }
}

extern "C" void kernel_launch(void* const* d_in, const int* in_sizes, int n_in,
                              void* d_out, int out_size, void* d_ws, size_t ws_size,
                              hipStream_t stream) {
    (void)in_sizes; (void)n_in; (void)out_size; (void)ws_size;
    const int*   x   = (const int*)  d_in[0];
    const float* emb = (const float*)d_in[1];
    const float* Wih = (const float*)d_in[2];
    const float* Whh = (const float*)d_in[3];
    const float* bih = (const float*)d_in[4];
    const float* bhh = (const float*)d_in[5];
    float* out = (float*)d_out;

    char* ws = (char*)d_ws;
    unsigned short* whh_f = (unsigned short*)(ws + WS_WHH_F);
    unsigned short* wih_f = (unsigned short*)(ws + WS_WIH_F);
    unsigned short* emb_f = (unsigned short*)(ws + WS_EMB_F);
    unsigned short* xgp   = (unsigned short*)(ws + WS_XG);
    float*          bias  = (float*)        (ws + WS_BIAS);
    unsigned*       hrec  = (unsigned*)      (ws + WS_HREC);

    init_k     <<<16, 256, 0, stream>>>(bih, bhh, bias);
    pack_frag  <<<dim3(256, 32), 64, 0, stream>>>(Whh, nullptr, whh_f);
    pack_frag  <<<dim3(256, 32), 64, 0, stream>>>(Wih, nullptr, wih_f);
    pack_frag  <<<dim3(256, 32), 64, 0, stream>>>(emb, x,       emb_f);
    gemm_k     <<<1024, 256, 0, stream>>>(emb_f, wih_f, bias, xgp);
    zero_hrec_k<<<8, 256, 0, stream>>>(hrec);          // after gemm: hrec aliases emb_f
    scan_k     <<<32, 512, 0, stream>>>(whh_f, xgp, hrec, out);
}